// Round 7
// baseline (4496.244 us; speedup 1.0000x reference)
//
#include <hip/hip_runtime.h>
#include <cstddef>

#define NPTS   40000
#define NGRP   256
#define GSZ    64
#define FDIM   768
#define BATCH  2

// FPS: one 512-thread block per batch, entirely on one CU. Coordinates live in
// VGPRs (79 pts/thread x 3 = 237 regs), running min-distance lives in LDS
// (thread-private slots). No inter-block communication at all.
#define FPS_TPB   512
#define FPS_PPT   79                    // ceil(40000/512)
#define FPS_SLOTS (FPS_TPB * FPS_PPT)   // 40448
#define FPS_ITERS (NGRP - 1)

#define NWORK     256                   // worker blocks; each does centers w and 256+w
#define GRID_BLK  (BATCH + NWORK)       // 258
#define NCHUNK    (NPTS / 64)           // 625

// knn key: high 48 bits = f64 dist bits (>=0, monotone), low 16 = idx (min-tie).
__device__ __forceinline__ unsigned long long knn_key(double v, int idx) {
    unsigned long long bits = (unsigned long long)__double_as_longlong(v);
    return (bits & 0xFFFFFFFFFFFF0000ull) | (unsigned long long)(unsigned)idx;
}

__global__ void __launch_bounds__(512, 2) fused_kernel(
    const float* __restrict__ xyz,            // (2, NPTS, 3)
    const float* __restrict__ fts,            // (2, NPTS, 768)
    const int*   __restrict__ valid,          // (2, NPTS)
    float* __restrict__ all_fts,              // (2,256,768) in d_out
    float* __restrict__ mask,                 // (2,256)     in d_out
    float* __restrict__ centers,              // (2,256,3)   in d_out
    unsigned int* __restrict__ flags)         // [512] per-center ready flags, pre-zeroed
{
    // one union'd LDS buffer so FPS and worker roles share the same 162 KB budget
    __shared__ __align__(16) unsigned char smem[FPS_SLOTS * 4 + 128];   // 161920 B
    const int bid  = blockIdx.x;
    const int t    = threadIdx.x;
    const int lane = t & 63;
    const int wid  = t >> 6;

    if (bid < BATCH) {
        // ======================= FPS role: 1 block = 1 batch = 1 CU ==========
        float* sdist = (float*)smem;                                     // [40448]
        unsigned long long* s_wkey = (unsigned long long*)(smem + FPS_SLOTS * 4); // [8]
        const int b = bid;
        const float* __restrict__ X = xyz + (size_t)b * NPTS * 3;

        float px[FPS_PPT], py[FPS_PPT], pz[FPS_PPT];
#pragma unroll
        for (int j = 0; j < FPS_PPT; ++j) {
            int idx = j * FPS_TPB + t;
            bool ok = idx < NPTS;
            int ii  = ok ? idx : 0;
            px[j] = X[ii * 3 + 0];
            py[j] = X[ii * 3 + 1];
            pz[j] = X[ii * 3 + 2];
            // sentinels: dist stays 0 forever -> can never beat a real point
            // (equal-0 ties lose on index since real chosen centers have smaller idx)
            sdist[j * FPS_TPB + t] = ok ? 1e10f : 0.0f;   // 1e10 matches reference init
        }

        float cx = X[0], cy = X[1], cz = X[2];
        if (t == 0) {
            centers[(size_t)(b * NGRP) * 3 + 0] = cx;
            centers[(size_t)(b * NGRP) * 3 + 1] = cy;
            centers[(size_t)(b * NGRP) * 3 + 2] = cz;
            __hip_atomic_store(&flags[b * NGRP], 1u,
                               __ATOMIC_RELEASE, __HIP_MEMORY_SCOPE_AGENT);
        }

        for (int it = 0; it < FPS_ITERS; ++it) {
            float bd = -1.0f; int bidx = 0;
#pragma unroll
            for (int j = 0; j < FPS_PPT; ++j) {
                float dx = px[j] - cx, dy = py[j] - cy, dz = pz[j] - cz;
                float d  = dx * dx + dy * dy + dz * dz;
                int   a  = j * FPS_TPB + t;
                float old = sdist[a];
                float nd  = fminf(old, d);
                if (nd < old) sdist[a] = nd;     // exec-masked write, saves LDS BW
                bool better = nd > bd;           // strict > keeps smallest index
                bd   = better ? nd : bd;
                bidx = better ? a  : bidx;
            }
            // key: f32 dist bits (>=0, monotone) << 16 | (0xFFFF - idx) tie-break
            unsigned long long key = ((unsigned long long)__float_as_uint(bd) << 16)
                                   | (unsigned long long)(0xFFFFu - (unsigned)bidx);
#pragma unroll
            for (int off = 32; off >= 1; off >>= 1) {
                unsigned long long o = __shfl_xor(key, off, 64);
                key = o > key ? o : key;
            }
            if (lane == 0) s_wkey[wid] = key;
            __syncthreads();
            unsigned long long g = s_wkey[lane & 7];
#pragma unroll
            for (int off = 4; off >= 1; off >>= 1) {
                unsigned long long o = __shfl_xor(g, off, 64);
                g = o > g ? o : g;
            }
            int widx = 0xFFFF - (int)(g & 0xFFFFull);
            cx = X[widx * 3 + 0]; cy = X[widx * 3 + 1]; cz = X[widx * 3 + 2];
            if (t == 0) {
                centers[(size_t)(b * NGRP + it + 1) * 3 + 0] = cx;
                centers[(size_t)(b * NGRP + it + 1) * 3 + 1] = cy;
                centers[(size_t)(b * NGRP + it + 1) * 3 + 2] = cz;
                __hip_atomic_store(&flags[b * NGRP + it + 1], 1u,
                                   __ATOMIC_RELEASE, __HIP_MEMORY_SCOPE_AGENT);
            }
            __syncthreads();   // protect s_wkey WAR for next iteration
        }
        return;
    }

    // =================== Worker role: centers w and 256+w ====================
    const int w = bid - BATCH;                 // [0, 256)
    unsigned long long* skey = (unsigned long long*)smem;   // [512]
    int* s_nbr = (int*)(smem + 4096);                       // [64]

    for (int half = 0; half < BATCH; ++half) {
        const int c = half * NGRP + w;
        const int b = half;
        const float* __restrict__ X = xyz + (size_t)b * NPTS * 3;

        // wait until this center is published
        {
            const unsigned int* fp = &flags[c];
            while (__hip_atomic_load(fp, __ATOMIC_RELAXED, __HIP_MEMORY_SCOPE_AGENT) == 0u)
                __builtin_amdgcn_s_sleep(32);
            __builtin_amdgcn_fence(__ATOMIC_ACQUIRE, "agent");
        }
        const double cx = (double)centers[(size_t)c * 3 + 0];
        const double cy = (double)centers[(size_t)c * 3 + 1];
        const double cz = (double)centers[(size_t)c * 3 + 2];

        // 8 waves: wave wid seeds from chunk wid, then scans chunks wid+8, wid+16, ...
        unsigned long long slot;
        {
            int i = wid * 64 + lane;
            float x = X[i * 3 + 0], y = X[i * 3 + 1], z = X[i * 3 + 2];
            double dx = (double)x - cx, dy = (double)y - cy, dz = (double)z - cz;
            slot = knn_key(dx * dx + dy * dy + dz * dz, i);
        }
        unsigned long long tau = slot;
#pragma unroll
        for (int off = 32; off >= 1; off >>= 1) {
            unsigned long long o = __shfl_xor(tau, off, 64);
            tau = o > tau ? o : tau;
        }

        float ax, ay, az, bx, by, bz;
        {
            int ia = (wid + 8) * 64 + lane;
            ax = X[ia * 3 + 0]; ay = X[ia * 3 + 1]; az = X[ia * 3 + 2];
            int sb = wid + 16 < NCHUNK ? wid + 16 : NCHUNK - 1;
            int ib = sb * 64 + lane;
            bx = X[ib * 3 + 0]; by = X[ib * 3 + 1]; bz = X[ib * 3 + 2];
        }
        for (int s = wid + 8; s < NCHUNK; s += 8) {
            float x = ax, y = ay, z = az;
            ax = bx; ay = by; az = bz;
            int sp = s + 16 < NCHUNK ? s + 16 : NCHUNK - 1;
            int ip = sp * 64 + lane;
            bx = X[ip * 3 + 0]; by = X[ip * 3 + 1]; bz = X[ip * 3 + 2];

            int i = s * 64 + lane;
            double dx = (double)x - cx, dy = (double)y - cy, dz = (double)z - cz;
            unsigned long long key = knn_key(dx * dx + dy * dy + dz * dz, i);

            unsigned long long cand = __ballot(key < tau);
            while (cand) {
                int l = __ffsll(cand) - 1;
                cand &= cand - 1;
                unsigned long long kc = __shfl(key, l, 64);
                if (kc < tau) {
                    unsigned long long om = __ballot(slot == tau);
                    int owner = __ffsll(om) - 1;
                    if (lane == owner) slot = kc;
                    unsigned long long tt = slot;
#pragma unroll
                    for (int off = 32; off >= 1; off >>= 1) {
                        unsigned long long o = __shfl_xor(tt, off, 64);
                        tt = o > tt ? o : tt;
                    }
                    tau = tt;
                }
            }
        }

        // exact merge of the 8 local top-64 sets: bitonic sort of 512 keys
        skey[t] = slot;
        __syncthreads();
        for (int k = 2; k <= 512; k <<= 1) {
            for (int j = k >> 1; j > 0; j >>= 1) {
                int ixj = t ^ j;
                if (ixj > t) {
                    unsigned long long a = skey[t], bb = skey[ixj];
                    bool up = ((t & k) == 0);
                    if ((a > bb) == up) { skey[t] = bb; skey[ixj] = a; }
                }
                __syncthreads();
            }
        }

        if (t < GSZ) {
            int idx = (int)(skey[t] & 0xFFFFull);
            s_nbr[t] = idx;
            int v = valid[b * NPTS + idx];
            unsigned long long vb = __ballot(v != 0);
            if (t == 0) mask[c] = vb ? 1.0f : 0.0f;
        }
        __syncthreads();

        // fused aggregation: 512 threads; dims [0,512) by all, [512,768) by t<256
        const float* __restrict__ F = fts + (size_t)b * NPTS * FDIM;
        float a0 = 0.f, a1 = 0.f, a2 = 0.f, a3 = 0.f;
        float b0 = 0.f, b1 = 0.f, b2 = 0.f, b3 = 0.f;
#pragma unroll 1
        for (int j = 0; j < GSZ; j += 4) {
            const float* r0 = F + (size_t)s_nbr[j + 0] * FDIM;
            const float* r1 = F + (size_t)s_nbr[j + 1] * FDIM;
            const float* r2 = F + (size_t)s_nbr[j + 2] * FDIM;
            const float* r3 = F + (size_t)s_nbr[j + 3] * FDIM;
            a0 += r0[t]; a1 += r1[t]; a2 += r2[t]; a3 += r3[t];
            if (t < FDIM - 512) {
                b0 += r0[512 + t]; b1 += r1[512 + t];
                b2 += r2[512 + t]; b3 += r3[512 + t];
            }
        }
        float* o = all_fts + (size_t)c * FDIM;
        o[t] = ((a0 + a1) + (a2 + a3)) * 0.015625f;
        if (t < FDIM - 512) o[512 + t] = ((b0 + b1) + (b2 + b3)) * 0.015625f;
        __syncthreads();   // skey/s_nbr reuse in next half
    }
}

extern "C" void kernel_launch(void* const* d_in, const int* in_sizes, int n_in,
                              void* d_out, int out_size, void* d_ws, size_t ws_size,
                              hipStream_t stream) {
    const float* xyz   = (const float*)d_in[0];
    const float* fts   = (const float*)d_in[1];
    const int*   valid = (const int*)d_in[2];

    float* out     = (float*)d_out;
    float* all_fts = out;                                  // (2,256,768)
    float* mask    = out + (size_t)BATCH * NGRP * FDIM;    // (2,256)
    float* centers = mask + (size_t)BATCH * NGRP;          // (2,256,3)

    unsigned int* flags = (unsigned int*)d_ws;             // 512 u32

    // flags must be zero at the start of EVERY call (harness never re-poisons)
    hipMemsetAsync(d_ws, 0, BATCH * NGRP * sizeof(unsigned int), stream);

    fused_kernel<<<dim3(GRID_BLK), dim3(512), 0, stream>>>(
        xyz, fts, valid, all_fts, mask, centers, flags);
}

// Round 8
// 4493.953 us; speedup vs baseline: 1.0005x; 1.0005x over previous
//
#include <hip/hip_runtime.h>
#include <cstddef>

#define NPTS   40000
#define NGRP   256
#define GSZ    64
#define FDIM   768
#define BATCH  2

// FPS: one 512-thread block per batch, entirely on one CU. Coordinates live in
// VGPRs (79 pts/thread x 3 = 237 regs; launch_bounds(512,1) -> 256-reg cap),
// running min-distance lives in LDS (thread-private slots, 2-way bank = free).
// No inter-block communication on the 255-iteration critical path.
#define FPS_TPB   512
#define FPS_PPT   79                    // ceil(40000/512)
#define FPS_SLOTS (FPS_TPB * FPS_PPT)   // 40448
#define FPS_ITERS (NGRP - 1)

#define NWORK     256                   // worker blocks; each does centers w and 256+w
#define GRID_BLK  (BATCH + NWORK)       // 258
#define NCHUNK    (NPTS / 64)           // 625

// knn key: high 48 bits = f64 dist bits (>=0, monotone), low 16 = idx (min-tie).
__device__ __forceinline__ unsigned long long knn_key(double v, int idx) {
    unsigned long long bits = (unsigned long long)__double_as_longlong(v);
    return (bits & 0xFFFFFFFFFFFF0000ull) | (unsigned long long)(unsigned)idx;
}

__global__ void __launch_bounds__(512, 1) fused_kernel(
    const float* __restrict__ xyz,            // (2, NPTS, 3)
    const float* __restrict__ fts,            // (2, NPTS, 768)
    const int*   __restrict__ valid,          // (2, NPTS)
    float* __restrict__ all_fts,              // (2,256,768) in d_out
    float* __restrict__ mask,                 // (2,256)     in d_out
    float* __restrict__ centers,              // (2,256,3)   in d_out
    unsigned int* __restrict__ flags)         // [512] per-center ready flags, pre-zeroed
{
    // one union'd LDS buffer so FPS and worker roles share the same budget
    __shared__ __align__(16) unsigned char smem[FPS_SLOTS * 4 + 128];   // 161920 B
    const int bid  = blockIdx.x;
    const int t    = threadIdx.x;
    const int lane = t & 63;
    const int wid  = t >> 6;

    if (bid < BATCH) {
        // ======================= FPS role: 1 block = 1 batch = 1 CU ==========
        float* sdist = (float*)smem;                                          // [40448]
        unsigned long long* s_wkey = (unsigned long long*)(smem + FPS_SLOTS * 4); // [8]
        const int b = bid;
        const float* __restrict__ X = xyz + (size_t)b * NPTS * 3;

        float px[FPS_PPT], py[FPS_PPT], pz[FPS_PPT];
#pragma unroll
        for (int j = 0; j < FPS_PPT; ++j) {
            int idx = j * FPS_TPB + t;
            bool ok = idx < NPTS;
            int ii  = ok ? idx : 0;
            px[j] = X[ii * 3 + 0];
            py[j] = X[ii * 3 + 1];
            pz[j] = X[ii * 3 + 2];
            // sentinels: dist stays 0 forever -> can never win (max dist > 0 always)
            sdist[j * FPS_TPB + t] = ok ? 1e10f : 0.0f;   // 1e10 matches reference init
        }

        float cx = X[0], cy = X[1], cz = X[2];
        if (t == 0) {
            centers[(size_t)(b * NGRP) * 3 + 0] = cx;
            centers[(size_t)(b * NGRP) * 3 + 1] = cy;
            centers[(size_t)(b * NGRP) * 3 + 2] = cz;
            __hip_atomic_store(&flags[b * NGRP], 1u,
                               __ATOMIC_RELEASE, __HIP_MEMORY_SCOPE_AGENT);
        }
        __syncthreads();

        for (int it = 0; it < FPS_ITERS; ++it) {
            float bd = -1.0f; int bidx = 0;
#pragma unroll
            for (int j = 0; j < FPS_PPT; ++j) {
                // EXACT reference arithmetic: ((dx*dx + dy*dy) + dz*dz), no fma
                float dx = px[j] - cx, dy = py[j] - cy, dz = pz[j] - cz;
                float d  = __fadd_rn(__fadd_rn(__fmul_rn(dx, dx), __fmul_rn(dy, dy)),
                                     __fmul_rn(dz, dz));
                int   a  = j * FPS_TPB + t;
                float old = sdist[a];
                float nd  = fminf(old, d);
                if (nd < old) sdist[a] = nd;     // exec-masked write
                bool better = nd > bd;           // strict > keeps smallest index
                bd   = better ? nd : bd;
                bidx = better ? a  : bidx;
            }
            // key: f32 dist bits (>=0, monotone) << 16 | (0xFFFF - idx) tie-break
            unsigned long long key = ((unsigned long long)__float_as_uint(bd) << 16)
                                   | (unsigned long long)(0xFFFFu - (unsigned)bidx);
#pragma unroll
            for (int off = 32; off >= 1; off >>= 1) {
                unsigned long long o = __shfl_xor(key, off, 64);
                key = o > key ? o : key;
            }
            if (lane == 0) s_wkey[wid] = key;
            __syncthreads();
            unsigned long long g = s_wkey[lane & 7];
#pragma unroll
            for (int off = 4; off >= 1; off >>= 1) {
                unsigned long long o = __shfl_xor(g, off, 64);
                g = o > g ? o : g;
            }
            int widx = 0xFFFF - (int)(g & 0xFFFFull);
            cx = X[widx * 3 + 0]; cy = X[widx * 3 + 1]; cz = X[widx * 3 + 2];
            if (t == 0) {
                centers[(size_t)(b * NGRP + it + 1) * 3 + 0] = cx;
                centers[(size_t)(b * NGRP + it + 1) * 3 + 1] = cy;
                centers[(size_t)(b * NGRP + it + 1) * 3 + 2] = cz;
                __hip_atomic_store(&flags[b * NGRP + it + 1], 1u,
                                   __ATOMIC_RELEASE, __HIP_MEMORY_SCOPE_AGENT);
            }
            __syncthreads();   // protect s_wkey WAR for next iteration
        }
        return;
    }

    // =================== Worker role: centers w and 256+w ====================
    const int w = bid - BATCH;                 // [0, 256)
    unsigned long long* skey = (unsigned long long*)smem;   // [512]
    int* s_nbr = (int*)(smem + 4096);                       // [64]

    for (int half = 0; half < BATCH; ++half) {
        const int c = half * NGRP + w;
        const int b = half;
        const float* __restrict__ X = xyz + (size_t)b * NPTS * 3;

        // wait until this center is published
        {
            const unsigned int* fp = &flags[c];
            while (__hip_atomic_load(fp, __ATOMIC_RELAXED, __HIP_MEMORY_SCOPE_AGENT) == 0u)
                __builtin_amdgcn_s_sleep(32);
            __builtin_amdgcn_fence(__ATOMIC_ACQUIRE, "agent");
        }
        const double cx = (double)centers[(size_t)c * 3 + 0];
        const double cy = (double)centers[(size_t)c * 3 + 1];
        const double cz = (double)centers[(size_t)c * 3 + 2];

        // 8 waves: wave wid seeds from chunk wid, then scans chunks wid+8, +16, ...
        unsigned long long slot;
        {
            int i = wid * 64 + lane;
            float x = X[i * 3 + 0], y = X[i * 3 + 1], z = X[i * 3 + 2];
            double dx = (double)x - cx, dy = (double)y - cy, dz = (double)z - cz;
            slot = knn_key(dx * dx + dy * dy + dz * dz, i);
        }
        unsigned long long tau = slot;
#pragma unroll
        for (int off = 32; off >= 1; off >>= 1) {
            unsigned long long o = __shfl_xor(tau, off, 64);
            tau = o > tau ? o : tau;
        }

        float ax, ay, az, bx, by, bz;
        {
            int ia = (wid + 8) * 64 + lane;
            ax = X[ia * 3 + 0]; ay = X[ia * 3 + 1]; az = X[ia * 3 + 2];
            int sb = wid + 16 < NCHUNK ? wid + 16 : NCHUNK - 1;
            int ib = sb * 64 + lane;
            bx = X[ib * 3 + 0]; by = X[ib * 3 + 1]; bz = X[ib * 3 + 2];
        }
        for (int s = wid + 8; s < NCHUNK; s += 8) {
            float x = ax, y = ay, z = az;
            ax = bx; ay = by; az = bz;
            int sp = s + 16 < NCHUNK ? s + 16 : NCHUNK - 1;
            int ip = sp * 64 + lane;
            bx = X[ip * 3 + 0]; by = X[ip * 3 + 1]; bz = X[ip * 3 + 2];

            int i = s * 64 + lane;
            double dx = (double)x - cx, dy = (double)y - cy, dz = (double)z - cz;
            unsigned long long key = knn_key(dx * dx + dy * dy + dz * dz, i);

            unsigned long long cand = __ballot(key < tau);
            while (cand) {
                int l = __ffsll(cand) - 1;
                cand &= cand - 1;
                unsigned long long kc = __shfl(key, l, 64);
                if (kc < tau) {
                    unsigned long long om = __ballot(slot == tau);
                    int owner = __ffsll(om) - 1;
                    if (lane == owner) slot = kc;
                    unsigned long long tt = slot;
#pragma unroll
                    for (int off = 32; off >= 1; off >>= 1) {
                        unsigned long long o = __shfl_xor(tt, off, 64);
                        tt = o > tt ? o : tt;
                    }
                    tau = tt;
                }
            }
        }

        // exact merge of the 8 local top-64 sets: bitonic sort of 512 keys
        skey[t] = slot;
        __syncthreads();
        for (int k = 2; k <= 512; k <<= 1) {
            for (int j = k >> 1; j > 0; j >>= 1) {
                int ixj = t ^ j;
                if (ixj > t) {
                    unsigned long long a = skey[t], bb = skey[ixj];
                    bool up = ((t & k) == 0);
                    if ((a > bb) == up) { skey[t] = bb; skey[ixj] = a; }
                }
                __syncthreads();
            }
        }

        if (t < GSZ) {
            int idx = (int)(skey[t] & 0xFFFFull);
            s_nbr[t] = idx;
            int v = valid[b * NPTS + idx];
            unsigned long long vb = __ballot(v != 0);
            if (t == 0) mask[c] = vb ? 1.0f : 0.0f;
        }
        __syncthreads();

        // fused aggregation: 512 threads; dims [0,512) by all, [512,768) by t<256
        const float* __restrict__ F = fts + (size_t)b * NPTS * FDIM;
        float a0 = 0.f, a1 = 0.f, a2 = 0.f, a3 = 0.f;
        float b0 = 0.f, b1 = 0.f, b2 = 0.f, b3 = 0.f;
#pragma unroll 1
        for (int j = 0; j < GSZ; j += 4) {
            const float* r0 = F + (size_t)s_nbr[j + 0] * FDIM;
            const float* r1 = F + (size_t)s_nbr[j + 1] * FDIM;
            const float* r2 = F + (size_t)s_nbr[j + 2] * FDIM;
            const float* r3 = F + (size_t)s_nbr[j + 3] * FDIM;
            a0 += r0[t]; a1 += r1[t]; a2 += r2[t]; a3 += r3[t];
            if (t < FDIM - 512) {
                b0 += r0[512 + t]; b1 += r1[512 + t];
                b2 += r2[512 + t]; b3 += r3[512 + t];
            }
        }
        float* o = all_fts + (size_t)c * FDIM;
        o[t] = ((a0 + a1) + (a2 + a3)) * 0.015625f;
        if (t < FDIM - 512) o[512 + t] = ((b0 + b1) + (b2 + b3)) * 0.015625f;
        __syncthreads();   // skey/s_nbr reuse in next half
    }
}

extern "C" void kernel_launch(void* const* d_in, const int* in_sizes, int n_in,
                              void* d_out, int out_size, void* d_ws, size_t ws_size,
                              hipStream_t stream) {
    const float* xyz   = (const float*)d_in[0];
    const float* fts   = (const float*)d_in[1];
    const int*   valid = (const int*)d_in[2];

    float* out     = (float*)d_out;
    float* all_fts = out;                                  // (2,256,768)
    float* mask    = out + (size_t)BATCH * NGRP * FDIM;    // (2,256)
    float* centers = mask + (size_t)BATCH * NGRP;          // (2,256,3)

    unsigned int* flags = (unsigned int*)d_ws;             // 512 u32

    // flags must be zero at the start of EVERY call (harness never re-poisons)
    hipMemsetAsync(d_ws, 0, BATCH * NGRP * sizeof(unsigned int), stream);

    fused_kernel<<<dim3(GRID_BLK), dim3(512), 0, stream>>>(
        xyz, fts, valid, all_fts, mask, centers, flags);
}

// Round 9
// 842.718 us; speedup vs baseline: 5.3354x; 5.3327x over previous
//
#include <hip/hip_runtime.h>
#include <cstddef>

#define NPTS   40000
#define NGRP   256
#define GSZ    64
#define FDIM   768
#define BATCH  2

// ---- FPS geometry (round-4 proven: 2.56 us/iter, no spill) ----
#define FPS_BPB    32                  // blocks per batch
#define FPS_NBLK   (FPS_BPB * BATCH)   // 64
#define FPS_PPB    (NPTS / FPS_BPB)    // 1250
#define FPS_PPT    20                  // ceil(1250/64)
#define FPS_ITERS  (NGRP - 1)

#define W_NBLK     (BATCH * NGRP)      // 512 worker blocks (one per center)
#define GRID_BLK   (FPS_NBLK + W_NBLK) // 576
#define NCHUNK     (NPTS / 64)         // 625

// fps key: high 48 bits = f64 dist bits (>=0, monotone), low 16 = 0xFFFF-idx
// (max-dist, tie -> min idx). Never zero.
__device__ __forceinline__ unsigned long long fps_key(double v, int idx) {
    unsigned long long bits = (unsigned long long)__double_as_longlong(v);
    return (bits & 0xFFFFFFFFFFFF0000ull) | (unsigned long long)(0xFFFFu - (unsigned)idx);
}
// knn key: min-dist, tie -> min idx.
__device__ __forceinline__ unsigned long long knn_key(double v, int idx) {
    unsigned long long bits = (unsigned long long)__double_as_longlong(v);
    return (bits & 0xFFFFFFFFFFFF0000ull) | (unsigned long long)(unsigned)idx;
}

__global__ void __launch_bounds__(256) fused_kernel(
    const float* __restrict__ xyz,            // (2, NPTS, 3)
    const float* __restrict__ fts,            // (2, NPTS, 768)
    const int*   __restrict__ valid,          // (2, NPTS)
    float* __restrict__ all_fts,              // (2,256,768) in d_out
    float* __restrict__ mask,                 // (2,256)     in d_out
    float* __restrict__ centers,              // (2,256,3)   in d_out
    unsigned long long* __restrict__ keys,    // [255][64] mailbox, pre-zeroed
    unsigned int* __restrict__ flags)         // [512] per-center ready flags, pre-zeroed
{
    // 128 KB static LDS footprint -> at most ONE block per CU (160 KB LDS/CU).
    // This structurally prevents worker blocks from stealing issue slots on the
    // 64 FPS CUs (the round-6 regression). Workers genuinely use the front of it.
    __shared__ __align__(16) unsigned char smem[131072];

    const int bid  = blockIdx.x;
    const int tid  = threadIdx.x;
    const int lane = tid & 63;
    const int wid  = tid >> 6;

    if (bid < FPS_NBLK) {
        // ================= FPS role: single wave per block (round-4 body) ====
        if (tid >= 64) return;               // waves 1..3 exit
        const int b    = bid >> 5;
        const int lb   = bid & 31;
        const float* __restrict__ X = xyz + (size_t)b * NPTS * 3;
        const int base  = lb * FPS_PPB;
        const int gbase = base + lane;

        double px[FPS_PPT], py[FPS_PPT], pz[FPS_PPT], dist[FPS_PPT];
#pragma unroll
        for (int j = 0; j < FPS_PPT; ++j) {
            int loc = lane + j * 64;
            bool ok = loc < FPS_PPB;
            int i   = base + (ok ? loc : 0);
            px[j]   = (double)X[i * 3 + 0];
            py[j]   = (double)X[i * 3 + 1];
            pz[j]   = (double)X[i * 3 + 2];
            dist[j] = ok ? 1e18 : -1.0;      // sentinels never win (valid dists >= 0)
        }

        double cx = (double)X[0], cy = (double)X[1], cz = (double)X[2];
        if (lb == 0 && lane == 0) {
            centers[(size_t)(b * NGRP) * 3 + 0] = X[0];
            centers[(size_t)(b * NGRP) * 3 + 1] = X[1];
            centers[(size_t)(b * NGRP) * 3 + 2] = X[2];
            __hip_atomic_store(&flags[b * NGRP], 1u,
                               __ATOMIC_RELEASE, __HIP_MEMORY_SCOPE_AGENT);
        }

        for (int it = 0; it < FPS_ITERS; ++it) {
            double bd = -2.0; int bj = 0;
#pragma unroll
            for (int j = 0; j < FPS_PPT; ++j) {
                double dx = px[j] - cx, dy = py[j] - cy, dz = pz[j] - cz;
                double d  = fma(dz, dz, fma(dy, dy, dx * dx));
                double nd = dist[j] < d ? dist[j] : d;
                dist[j] = nd;
                bool better = nd > bd;       // strict > keeps smallest j (= smallest idx)
                bd = better ? nd : bd;
                bj = better ? j  : bj;
            }
            unsigned long long key = fps_key(bd, gbase + (bj << 6));
#pragma unroll
            for (int off = 32; off >= 1; off >>= 1) {
                unsigned long long o = __shfl_xor(key, off, 64);
                key = o > key ? o : key;
            }
            if (lane == 0)
                __hip_atomic_store(&keys[it * FPS_NBLK + bid], key,
                                   __ATOMIC_RELAXED, __HIP_MEMORY_SCOPE_AGENT);

            // 32 lanes poll the batch's 32 fresh slots (one coalesced round)
            unsigned long long pk = 0;
            if (lane < FPS_BPB) {
                const unsigned long long* sp = &keys[it * FPS_NBLK + b * FPS_BPB + lane];
                do {
                    pk = __hip_atomic_load(sp, __ATOMIC_RELAXED, __HIP_MEMORY_SCOPE_AGENT);
                } while (pk == 0ull);
            }
            unsigned long long g = pk;
#pragma unroll
            for (int off = 16; off >= 1; off >>= 1) {
                unsigned long long o = __shfl_xor(g, off, 64);
                g = o > g ? o : g;
            }
            g = __shfl(g, 0, 64);
            int widx = 0xFFFF - (int)(g & 0xFFFFull);
            float wx = X[widx * 3 + 0], wy = X[widx * 3 + 1], wz = X[widx * 3 + 2];
            cx = (double)wx; cy = (double)wy; cz = (double)wz;
            if (lb == 0 && lane == 0) {
                centers[(size_t)(b * NGRP + it + 1) * 3 + 0] = wx;
                centers[(size_t)(b * NGRP + it + 1) * 3 + 1] = wy;
                centers[(size_t)(b * NGRP + it + 1) * 3 + 2] = wz;
                __hip_atomic_store(&flags[b * NGRP + it + 1], 1u,
                                   __ATOMIC_RELEASE, __HIP_MEMORY_SCOPE_AGENT);
            }
        }
        return;
    }

    // ================= Worker role: one block per center (knn + agg + mask) ====
    // Interleave batches in dispatch order so both batches' center-k workers
    // enter the machine together (centers publish pairwise at ~the same time).
    const int w = bid - FPS_NBLK;              // [0, 512)
    const int c = (w >> 1) + ((w & 1) << 8);   // even -> batch0, odd -> batch1
    const int b = c >> 8;
    const float* __restrict__ X = xyz + (size_t)b * NPTS * 3;

    unsigned long long* skey = (unsigned long long*)smem;   // [256]
    int* s_nbr = (int*)(smem + 2048);                       // [64]

    // wait until this center is published
    {
        const unsigned int* fp = &flags[c];
        while (__hip_atomic_load(fp, __ATOMIC_RELAXED, __HIP_MEMORY_SCOPE_AGENT) == 0u)
            __builtin_amdgcn_s_sleep(64);
        __builtin_amdgcn_fence(__ATOMIC_ACQUIRE, "agent");
    }

    const double cx = (double)centers[(size_t)c * 3 + 0];
    const double cy = (double)centers[(size_t)c * 3 + 1];
    const double cz = (double)centers[(size_t)c * 3 + 2];

    // wave `wid` owns chunks s ≡ wid (mod 4); its first chunk seeds the slots
    unsigned long long slot;
    {
        int i = wid * 64 + lane;
        float x = X[i * 3 + 0], y = X[i * 3 + 1], z = X[i * 3 + 2];
        double dx = (double)x - cx, dy = (double)y - cy, dz = (double)z - cz;
        slot = knn_key(dx * dx + dy * dy + dz * dz, i);
    }
    unsigned long long tau = slot;
#pragma unroll
    for (int off = 32; off >= 1; off >>= 1) {
        unsigned long long o = __shfl_xor(tau, off, 64);
        tau = o > tau ? o : tau;
    }

    // depth-2 software prefetch over this wave's chunk list
    float ax, ay, az, bx, by, bz;
    {
        int ia = (wid + 4) * 64 + lane;
        ax = X[ia * 3 + 0]; ay = X[ia * 3 + 1]; az = X[ia * 3 + 2];
        int sb = wid + 8 < NCHUNK ? wid + 8 : NCHUNK - 1;
        int ib = sb * 64 + lane;
        bx = X[ib * 3 + 0]; by = X[ib * 3 + 1]; bz = X[ib * 3 + 2];
    }
    for (int s = wid + 4; s < NCHUNK; s += 4) {
        float x = ax, y = ay, z = az;
        ax = bx; ay = by; az = bz;
        int sp = s + 8 < NCHUNK ? s + 8 : NCHUNK - 1;
        int ip = sp * 64 + lane;
        bx = X[ip * 3 + 0]; by = X[ip * 3 + 1]; bz = X[ip * 3 + 2];

        int i = s * 64 + lane;
        double dx = (double)x - cx, dy = (double)y - cy, dz = (double)z - cz;
        unsigned long long key = knn_key(dx * dx + dy * dy + dz * dz, i);

        unsigned long long cand = __ballot(key < tau);
        while (cand) {
            int l = __ffsll(cand) - 1;
            cand &= cand - 1;
            unsigned long long kc = __shfl(key, l, 64);
            if (kc < tau) {
                unsigned long long om = __ballot(slot == tau);
                int owner = __ffsll(om) - 1;
                if (lane == owner) slot = kc;
                unsigned long long tt = slot;
#pragma unroll
                for (int off = 32; off >= 1; off >>= 1) {
                    unsigned long long o = __shfl_xor(tt, off, 64);
                    tt = o > tt ? o : tt;
                }
                tau = tt;
            }
        }
    }

    // exact merge of the 4 local top-64 sets: bitonic sort of 256 keys in LDS
    skey[tid] = slot;
    __syncthreads();
#pragma unroll
    for (int k = 2; k <= 256; k <<= 1) {
        for (int j = k >> 1; j > 0; j >>= 1) {
            int ixj = tid ^ j;
            if (ixj > tid) {
                unsigned long long a = skey[tid], bb = skey[ixj];
                bool up = ((tid & k) == 0);
                if ((a > bb) == up) { skey[tid] = bb; skey[ixj] = a; }
            }
            __syncthreads();
        }
    }

    if (wid == 0) {
        int idx = (int)(skey[lane] & 0xFFFFull);
        s_nbr[lane] = idx;
        int v = valid[b * NPTS + idx];
        unsigned long long vb = __ballot(v != 0);
        if (lane == 0) mask[c] = vb ? 1.0f : 0.0f;
    }
    __syncthreads();

    // fused aggregation: 256 threads cover 768 dims (3 each), 6 acc chains
    const float* __restrict__ F = fts + (size_t)b * NPTS * FDIM;
    float a0 = 0.f, a1 = 0.f, a2 = 0.f, b0 = 0.f, b1 = 0.f, b2 = 0.f;
#pragma unroll 1
    for (int j = 0; j < GSZ; j += 2) {
        const float* r0 = F + (size_t)s_nbr[j]     * FDIM;
        const float* r1 = F + (size_t)s_nbr[j + 1] * FDIM;
        a0 += r0[tid];       b0 += r1[tid];
        a1 += r0[tid + 256]; b1 += r1[tid + 256];
        a2 += r0[tid + 512]; b2 += r1[tid + 512];
    }
    float* o = all_fts + (size_t)c * FDIM;
    o[tid]       = (a0 + b0) * 0.015625f;
    o[tid + 256] = (a1 + b1) * 0.015625f;
    o[tid + 512] = (a2 + b2) * 0.015625f;
}

extern "C" void kernel_launch(void* const* d_in, const int* in_sizes, int n_in,
                              void* d_out, int out_size, void* d_ws, size_t ws_size,
                              hipStream_t stream) {
    const float* xyz   = (const float*)d_in[0];
    const float* fts   = (const float*)d_in[1];
    const int*   valid = (const int*)d_in[2];

    float* out     = (float*)d_out;
    float* all_fts = out;                                  // (2,256,768)
    float* mask    = out + (size_t)BATCH * NGRP * FDIM;    // (2,256)
    float* centers = mask + (size_t)BATCH * NGRP;          // (2,256,3)

    unsigned long long* keys  = (unsigned long long*)d_ws;             // 255*64*8 = 130560 B
    unsigned int*       flags = (unsigned int*)((char*)d_ws + 130560); // 512*4 = 2048 B

    // mailbox + flags must be zero at the start of EVERY call
    hipMemsetAsync(d_ws, 0, 132608, stream);

    fused_kernel<<<dim3(GRID_BLK), dim3(256), 0, stream>>>(
        xyz, fts, valid, all_fts, mask, centers, keys, flags);
}

// Round 10
// 806.463 us; speedup vs baseline: 5.5753x; 1.0450x over previous
//
#include <hip/hip_runtime.h>
#include <cstddef>

#define NPTS   40000
#define NGRP   256
#define GSZ    64
#define FDIM   768
#define BATCH  2

// ---------------- FPS geometry (R4-proven block layout) ----------------
#define FPS_BPB    32                  // blocks per batch
#define FPS_NBLK   (FPS_BPB * BATCH)   // 64
#define FPS_TPB    64
#define FPS_PPB    (NPTS / FPS_BPB)    // 1250
#define FPS_PPT    20                  // ceil(1250/64)

// speculative multi-step parameters
#define SPEC_M     8                   // top-M keys per block per round
#define SPEC_S     4                   // max accepted centers per round
#define MB_RWORDS  (FPS_NBLK * SPEC_M) // 512 u64 per round
#define MB_ROUNDS  255                 // hard bound (>=1 accept per round)
#define MB_BYTES   ((size_t)MB_ROUNDS * MB_RWORDS * 8)   // 1,044,480

#define NCHUNK     (NPTS / 64)         // 625

// fps key: high 48 bits = f64 dist bits (>=0, monotone as integer),
// low 16 = 0xFFFF - idx (max-dist, tie -> min idx). Never zero.
__device__ __forceinline__ unsigned long long fps_key(double v, unsigned tb) {
    unsigned long long bits = (unsigned long long)__double_as_longlong(v);
    return (bits & 0xFFFFFFFFFFFF0000ull) | (unsigned long long)tb;
}
// knn key: min-dist, tie -> min idx.
__device__ __forceinline__ unsigned long long knn_key(double v, int idx) {
    unsigned long long bits = (unsigned long long)__double_as_longlong(v);
    return (bits & 0xFFFFFFFFFFFF0000ull) | (unsigned long long)(unsigned)idx;
}
// R4-proven distance formula (f32 inputs, f64 math) — used EVERYWHERE in FPS.
__device__ __forceinline__ double d3(float px, float py, float pz,
                                     double cx, double cy, double cz) {
    double dx = (double)px - cx, dy = (double)py - cy, dz = (double)pz - cz;
    return fma(dz, dz, fma(dy, dy, dx * dx));
}
__device__ __forceinline__ unsigned long long wave_max_u64(unsigned long long k) {
#pragma unroll
    for (int off = 32; off >= 1; off >>= 1) {
        unsigned long long o = __shfl_xor(k, off, 64);
        k = o > k ? o : k;
    }
    return k;
}

// ---------------- speculative FPS: 64 blocks x 64 threads ----------------
__global__ void __launch_bounds__(FPS_TPB) fps_spec_kernel(
    const float* __restrict__ xyz,            // (2, NPTS, 3)
    float* __restrict__ centers,              // (2, NGRP, 3) in d_out
    unsigned long long* __restrict__ mb)      // [MB_ROUNDS][512], pre-zeroed
{
    const int bid  = blockIdx.x;
    const int b    = bid >> 5;
    const int lb   = bid & 31;
    const int lane = threadIdx.x;
    const float* __restrict__ X = xyz + (size_t)b * NPTS * 3;
    const int base = lb * FPS_PPB;

    float  px[FPS_PPT], py[FPS_PPT], pz[FPS_PPT];
    double dist[FPS_PPT];
    unsigned valmask = 0;
#pragma unroll
    for (int j = 0; j < FPS_PPT; ++j) {
        int loc = lane + j * FPS_TPB;
        bool ok = loc < FPS_PPB;
        int i   = base + (ok ? loc : 0);
        px[j] = X[i * 3 + 0]; py[j] = X[i * 3 + 1]; pz[j] = X[i * 3 + 2];
        if (ok) valmask |= 1u << j;
    }

    // center 0 = point 0 of the batch
    double cx = (double)X[0], cy = (double)X[1], cz = (double)X[2];
    if (lb == 0 && lane == 0) {
        centers[(size_t)(b * NGRP) * 3 + 0] = X[0];
        centers[(size_t)(b * NGRP) * 3 + 1] = X[1];
        centers[(size_t)(b * NGRP) * 3 + 2] = X[2];
    }
#pragma unroll
    for (int j = 0; j < FPS_PPT; ++j)
        dist[j] = d3(px[j], py[j], pz[j], cx, cy, cz);   // (invalid lanes masked later)

    const unsigned tb0 = 0xFFFFu - (unsigned)(base + lane);
    int done = 1;
    int r = 0;

    while (done < NGRP) {
        // ---- build keys from current dists ----
        unsigned long long k[FPS_PPT];
#pragma unroll
        for (int j = 0; j < FPS_PPT; ++j)
            k[j] = fps_key(dist[j], tb0 - (unsigned)(j << 6));

        // ---- extract block top-8 (8 iterated wave-max extractions) ----
        unsigned cons = ~valmask;                 // consumed/invalid bits
        unsigned long long msg0, msg1, msg2, msg3, msg4, msg5, msg6, msg7;
        unsigned long long gk;
#define EXTRACT(MSG)                                                        \
        {                                                                   \
            unsigned long long bk = 0; int bj = 0;                          \
            _Pragma("unroll")                                               \
            for (int j = 0; j < FPS_PPT; ++j) {                             \
                bool live = ((cons >> j) & 1u) == 0u;                       \
                unsigned long long kk = live ? k[j] : 0ull;                 \
                if (kk > bk) { bk = kk; bj = j; }                           \
            }                                                               \
            gk = wave_max_u64(bk);                                          \
            if (bk == gk && bk != 0ull) cons |= 1u << bj;                   \
            MSG = gk;                                                       \
        }
        EXTRACT(msg0) EXTRACT(msg1) EXTRACT(msg2) EXTRACT(msg3)
        EXTRACT(msg4) EXTRACT(msg5) EXTRACT(msg6) EXTRACT(msg7)
#undef EXTRACT

        // ---- publish: lanes 0..7 store msg[lane] (static select) ----
        if (lane < SPEC_M) {
            unsigned long long v = msg0;
            v = (lane == 1) ? msg1 : v;  v = (lane == 2) ? msg2 : v;
            v = (lane == 3) ? msg3 : v;  v = (lane == 4) ? msg4 : v;
            v = (lane == 5) ? msg5 : v;  v = (lane == 6) ? msg6 : v;
            v = (lane == 7) ? msg7 : v;
            __hip_atomic_store(&mb[(size_t)r * MB_RWORDS + bid * SPEC_M + lane], v,
                               __ATOMIC_RELAXED, __HIP_MEMORY_SCOPE_AGENT);
        }

        // ---- poll this batch's 256 fresh words (4 per lane, coalesced) ----
        const unsigned long long* pb = mb + (size_t)r * MB_RWORDS + b * (FPS_BPB * SPEC_M);
        unsigned long long w0, w1, w2, w3;
        w0 = __hip_atomic_load(pb + lane,       __ATOMIC_RELAXED, __HIP_MEMORY_SCOPE_AGENT);
        w1 = __hip_atomic_load(pb + lane + 64,  __ATOMIC_RELAXED, __HIP_MEMORY_SCOPE_AGENT);
        w2 = __hip_atomic_load(pb + lane + 128, __ATOMIC_RELAXED, __HIP_MEMORY_SCOPE_AGENT);
        w3 = __hip_atomic_load(pb + lane + 192, __ATOMIC_RELAXED, __HIP_MEMORY_SCOPE_AGENT);
        for (;;) {
            bool miss = (w0 == 0ull) | (w1 == 0ull) | (w2 == 0ull) | (w3 == 0ull);
            if (__ballot(miss) == 0ull) break;
            if (w0 == 0ull) w0 = __hip_atomic_load(pb + lane,       __ATOMIC_RELAXED, __HIP_MEMORY_SCOPE_AGENT);
            if (w1 == 0ull) w1 = __hip_atomic_load(pb + lane + 64,  __ATOMIC_RELAXED, __HIP_MEMORY_SCOPE_AGENT);
            if (w2 == 0ull) w2 = __hip_atomic_load(pb + lane + 128, __ATOMIC_RELAXED, __HIP_MEMORY_SCOPE_AGENT);
            if (w3 == 0ull) w3 = __hip_atomic_load(pb + lane + 192, __ATOMIC_RELAXED, __HIP_MEMORY_SCOPE_AGENT);
        }

        // ---- guard threshold T = max over blocks of their 8th key ----
        unsigned long long tl = 0;
        if ((lane & 7) == 7) {
            tl = w0 > w1 ? w0 : w1;
            tl = w2 > tl ? w2 : tl;
            tl = w3 > tl ? w3 : tl;
        }
        const unsigned long long T = wave_max_u64(tl);

        // ---- decode my 4 candidates: value (trunc48), tiebreak, coords ----
        double v0, v1, v2, v3;
        unsigned t0, t1, t2, t3;
        float c0x, c0y, c0z, c1x, c1y, c1z, c2x, c2y, c2z, c3x, c3y, c3z;
#define DECODE(W, V, TB, CX, CY, CZ)                                        \
        {                                                                   \
            TB = (unsigned)(W & 0xFFFFull);                                 \
            V  = __longlong_as_double((long long)(W & 0xFFFFFFFFFFFF0000ull)); \
            int ii = (int)(0xFFFFu - TB);                                   \
            CX = X[ii * 3 + 0]; CY = X[ii * 3 + 1]; CZ = X[ii * 3 + 2];     \
        }
        DECODE(w0, v0, t0, c0x, c0y, c0z)
        DECODE(w1, v1, t1, c1x, c1y, c1z)
        DECODE(w2, v2, t2, c2x, c2y, c2z)
        DECODE(w3, v3, t3, c3x, c3y, c3z)
#undef DECODE

        // ---- speculative chain: up to SPEC_S exact winners ----
        double wsx[SPEC_S], wsy[SPEC_S], wsz[SPEC_S];
        int A = 0;
#pragma unroll
        for (int s = 0; s < SPEC_S; ++s) {
            if (A == s) {   // only proceed if previous step accepted
                unsigned long long bk = fps_key(v0, t0);
                unsigned long long kq = fps_key(v1, t1); bk = kq > bk ? kq : bk;
                kq = fps_key(v2, t2); bk = kq > bk ? kq : bk;
                kq = fps_key(v3, t3); bk = kq > bk ? kq : bk;
                unsigned long long g = wave_max_u64(bk);
                if (s == 0 || g >= T) {     // s=0 is the true full argmax; else guard
                    int widx = (int)(0xFFFFu - (unsigned)(g & 0xFFFFull));
                    float wx = X[widx * 3 + 0], wy = X[widx * 3 + 1], wz = X[widx * 3 + 2];
                    if (lb == 0 && lane == 0) {
                        centers[((size_t)b * NGRP + done) * 3 + 0] = wx;
                        centers[((size_t)b * NGRP + done) * 3 + 1] = wy;
                        centers[((size_t)b * NGRP + done) * 3 + 2] = wz;
                    }
                    double Wx = (double)wx, Wy = (double)wy, Wz = (double)wz;
                    v0 = fmin(v0, d3(c0x, c0y, c0z, Wx, Wy, Wz));
                    v1 = fmin(v1, d3(c1x, c1y, c1z, Wx, Wy, Wz));
                    v2 = fmin(v2, d3(c2x, c2y, c2z, Wx, Wy, Wz));
                    v3 = fmin(v3, d3(c3x, c3y, c3z, Wx, Wy, Wz));
                    wsx[s] = Wx; wsy[s] = Wy; wsz[s] = Wz;
                    A = s + 1;
                    ++done;
                    if (done == NGRP) break;
                }
            }
        }

        // ---- update local dists vs the A accepted centers (static idx) ----
#pragma unroll
        for (int s = 0; s < SPEC_S; ++s) {
            if (s < A) {
#pragma unroll
                for (int j = 0; j < FPS_PPT; ++j)
                    dist[j] = fmin(dist[j], d3(px[j], py[j], pz[j],
                                               wsx[s], wsy[s], wsz[s]));
            }
        }
        ++r;
    }
}

// ---------------- R4-proven fallback FPS (1 key/block/iter) ----------------
__global__ void __launch_bounds__(FPS_TPB) fps_kernel(
    const float* __restrict__ xyz,
    float* __restrict__ centers,
    unsigned long long* __restrict__ keys)    // [255][64], pre-zeroed
{
    const int bid  = blockIdx.x;
    const int b    = bid >> 5;
    const int lb   = bid & 31;
    const int lane = threadIdx.x;
    const float* __restrict__ X = xyz + (size_t)b * NPTS * 3;
    const int base  = lb * FPS_PPB;
    const int gbase = base + lane;

    double px[FPS_PPT], py[FPS_PPT], pz[FPS_PPT], dist[FPS_PPT];
#pragma unroll
    for (int j = 0; j < FPS_PPT; ++j) {
        int loc = lane + j * FPS_TPB;
        bool ok = loc < FPS_PPB;
        int i   = base + (ok ? loc : 0);
        px[j] = (double)X[i * 3 + 0];
        py[j] = (double)X[i * 3 + 1];
        pz[j] = (double)X[i * 3 + 2];
        dist[j] = ok ? 1e18 : -1.0;
    }
    double cx = (double)X[0], cy = (double)X[1], cz = (double)X[2];
    if (lb == 0 && lane == 0) {
        centers[(size_t)(b * NGRP) * 3 + 0] = X[0];
        centers[(size_t)(b * NGRP) * 3 + 1] = X[1];
        centers[(size_t)(b * NGRP) * 3 + 2] = X[2];
    }
    for (int it = 0; it < NGRP - 1; ++it) {
        double bd = -2.0; int bj = 0;
#pragma unroll
        for (int j = 0; j < FPS_PPT; ++j) {
            double dx = px[j] - cx, dy = py[j] - cy, dz = pz[j] - cz;
            double d  = fma(dz, dz, fma(dy, dy, dx * dx));
            double nd = dist[j] < d ? dist[j] : d;
            dist[j] = nd;
            bool better = nd > bd;
            bd = better ? nd : bd;
            bj = better ? j  : bj;
        }
        unsigned long long key = fps_key(bd, 0xFFFFu - (unsigned)(gbase + (bj << 6)));
        key = wave_max_u64(key);
        if (lane == 0)
            __hip_atomic_store(&keys[it * FPS_NBLK + bid], key,
                               __ATOMIC_RELAXED, __HIP_MEMORY_SCOPE_AGENT);
        unsigned long long pk = 0;
        if (lane < FPS_BPB) {
            const unsigned long long* sp = &keys[it * FPS_NBLK + b * FPS_BPB + lane];
            do {
                pk = __hip_atomic_load(sp, __ATOMIC_RELAXED, __HIP_MEMORY_SCOPE_AGENT);
            } while (pk == 0ull);
        }
        unsigned long long g = wave_max_u64(pk);
        int widx = 0xFFFF - (int)(g & 0xFFFFull);
        float wx = X[widx * 3 + 0], wy = X[widx * 3 + 1], wz = X[widx * 3 + 2];
        cx = (double)wx; cy = (double)wy; cz = (double)wz;
        if (lb == 0 && lane == 0) {
            centers[(size_t)(b * NGRP + it + 1) * 3 + 0] = wx;
            centers[(size_t)(b * NGRP + it + 1) * 3 + 1] = wy;
            centers[(size_t)(b * NGRP + it + 1) * 3 + 2] = wz;
        }
    }
}

// ---------------- KNN: 512 blocks x 256 threads (R4-proven) ----------------
__global__ void __launch_bounds__(256) knn_kernel(
    const float* __restrict__ xyz,
    const int*   __restrict__ valid,
    const float* __restrict__ centers,
    int*   __restrict__ knn_idx,
    float* __restrict__ mask)
{
    const int c    = blockIdx.x;
    const int b    = c >> 8;
    const int tid  = threadIdx.x;
    const int wid  = tid >> 6;
    const int lane = tid & 63;
    const float* __restrict__ X = xyz + (size_t)b * NPTS * 3;

    const double cx = (double)centers[(size_t)c * 3 + 0];
    const double cy = (double)centers[(size_t)c * 3 + 1];
    const double cz = (double)centers[(size_t)c * 3 + 2];

    unsigned long long slot;
    {
        int i = wid * 64 + lane;
        float x = X[i * 3 + 0], y = X[i * 3 + 1], z = X[i * 3 + 2];
        double dx = (double)x - cx, dy = (double)y - cy, dz = (double)z - cz;
        slot = knn_key(dx * dx + dy * dy + dz * dz, i);
    }
    unsigned long long tau = wave_max_u64(slot);

    float ax, ay, az, bx, by, bz;
    {
        int ia = (wid + 4) * 64 + lane;
        ax = X[ia * 3 + 0]; ay = X[ia * 3 + 1]; az = X[ia * 3 + 2];
        int sb = wid + 8 < NCHUNK ? wid + 8 : NCHUNK - 1;
        int ib = sb * 64 + lane;
        bx = X[ib * 3 + 0]; by = X[ib * 3 + 1]; bz = X[ib * 3 + 2];
    }
    for (int s = wid + 4; s < NCHUNK; s += 4) {
        float x = ax, y = ay, z = az;
        ax = bx; ay = by; az = bz;
        int sp = s + 8 < NCHUNK ? s + 8 : NCHUNK - 1;
        int ip = sp * 64 + lane;
        bx = X[ip * 3 + 0]; by = X[ip * 3 + 1]; bz = X[ip * 3 + 2];

        int i = s * 64 + lane;
        double dx = (double)x - cx, dy = (double)y - cy, dz = (double)z - cz;
        unsigned long long key = knn_key(dx * dx + dy * dy + dz * dz, i);

        unsigned long long cand = __ballot(key < tau);
        while (cand) {
            int l = __ffsll(cand) - 1;
            cand &= cand - 1;
            unsigned long long kc = __shfl(key, l, 64);
            if (kc < tau) {
                unsigned long long om = __ballot(slot == tau);
                int owner = __ffsll(om) - 1;
                if (lane == owner) slot = kc;
                tau = wave_max_u64(slot);
            }
        }
    }

    __shared__ unsigned long long skey[256];
    skey[tid] = slot;
    __syncthreads();
#pragma unroll
    for (int k = 2; k <= 256; k <<= 1) {
        for (int j = k >> 1; j > 0; j >>= 1) {
            int ixj = tid ^ j;
            if (ixj > tid) {
                unsigned long long a = skey[tid], bb = skey[ixj];
                bool up = ((tid & k) == 0);
                if ((a > bb) == up) { skey[tid] = bb; skey[ixj] = a; }
            }
            __syncthreads();
        }
    }
    if (wid == 0) {
        int idx = (int)(skey[lane] & 0xFFFFull);
        knn_idx[c * GSZ + lane] = idx;
        int v = valid[b * NPTS + idx];
        unsigned long long vb = __ballot(v != 0);
        if (lane == 0) mask[c] = vb ? 1.0f : 0.0f;
    }
}

// ---------------- Aggregation: 512 blocks x 768 threads (R4-proven) ----------------
__global__ void __launch_bounds__(FDIM) agg_kernel(
    const float* __restrict__ fts,
    const int*   __restrict__ knn_idx,
    float* __restrict__ all_fts)
{
    const int c   = blockIdx.x;
    const int b   = c >> 8;
    const int tid = threadIdx.x;
    __shared__ int nbr[GSZ];
    if (tid < GSZ) nbr[tid] = knn_idx[c * GSZ + tid];
    __syncthreads();
    const float* __restrict__ F = fts + (size_t)b * NPTS * FDIM;
    float a0 = 0.f, a1 = 0.f, a2 = 0.f, a3 = 0.f;
    float a4 = 0.f, a5 = 0.f, a6 = 0.f, a7 = 0.f;
#pragma unroll 1
    for (int j = 0; j < GSZ; j += 8) {
        a0 += F[(size_t)nbr[j + 0] * FDIM + tid];
        a1 += F[(size_t)nbr[j + 1] * FDIM + tid];
        a2 += F[(size_t)nbr[j + 2] * FDIM + tid];
        a3 += F[(size_t)nbr[j + 3] * FDIM + tid];
        a4 += F[(size_t)nbr[j + 4] * FDIM + tid];
        a5 += F[(size_t)nbr[j + 5] * FDIM + tid];
        a6 += F[(size_t)nbr[j + 6] * FDIM + tid];
        a7 += F[(size_t)nbr[j + 7] * FDIM + tid];
    }
    all_fts[(size_t)c * FDIM + tid] =
        (((a0 + a1) + (a2 + a3)) + ((a4 + a5) + (a6 + a7))) * 0.015625f;
}

extern "C" void kernel_launch(void* const* d_in, const int* in_sizes, int n_in,
                              void* d_out, int out_size, void* d_ws, size_t ws_size,
                              hipStream_t stream) {
    const float* xyz   = (const float*)d_in[0];
    const float* fts   = (const float*)d_in[1];
    const int*   valid = (const int*)d_in[2];

    float* out     = (float*)d_out;
    float* all_fts = out;                                  // (2,256,768)
    float* mask    = out + (size_t)BATCH * NGRP * FDIM;    // (2,256)
    float* centers = mask + (size_t)BATCH * NGRP;          // (2,256,3)

    const size_t need_spec = MB_BYTES + (size_t)BATCH * NGRP * GSZ * 4;

    if (ws_size >= need_spec) {
        unsigned long long* mb = (unsigned long long*)d_ws;
        int* knn_idx = (int*)((char*)d_ws + MB_BYTES);
        hipMemsetAsync(d_ws, 0, MB_BYTES, stream);   // fresh mailbox every call
        fps_spec_kernel<<<dim3(FPS_NBLK), dim3(FPS_TPB), 0, stream>>>(xyz, centers, mb);
        knn_kernel<<<dim3(BATCH * NGRP), dim3(256), 0, stream>>>(xyz, valid, centers, knn_idx, mask);
        agg_kernel<<<dim3(BATCH * NGRP), dim3(FDIM), 0, stream>>>(fts, knn_idx, all_fts);
    } else {
        // fallback: R4-proven path (small workspace)
        unsigned long long* keys = (unsigned long long*)d_ws;   // 255*64*8 = 130560 B
        int* knn_idx = (int*)((char*)d_ws + 131072);            // 512*64*4
        hipMemsetAsync(d_ws, 0, 131072, stream);
        fps_kernel<<<dim3(FPS_NBLK), dim3(FPS_TPB), 0, stream>>>(xyz, centers, keys);
        knn_kernel<<<dim3(BATCH * NGRP), dim3(256), 0, stream>>>(xyz, valid, centers, knn_idx, mask);
        agg_kernel<<<dim3(BATCH * NGRP), dim3(FDIM), 0, stream>>>(fts, knn_idx, all_fts);
    }
}

// Round 11
// 658.924 us; speedup vs baseline: 6.8236x; 1.2239x over previous
//
#include <hip/hip_runtime.h>
#include <cstddef>

#define NPTS   40000
#define NGRP   256
#define GSZ    64
#define FDIM   768
#define BATCH  2

// ---------------- FPS geometry (R4-proven block layout) ----------------
#define FPS_BPB    32                  // blocks per batch
#define FPS_NBLK   (FPS_BPB * BATCH)   // 64
#define FPS_TPB    64
#define FPS_PPB    (NPTS / FPS_BPB)    // 1250
#define FPS_PPT    20                  // ceil(1250/64)

// speculative multi-step parameters
#define SPEC_M     16                  // top-M keys per block per round
#define SPEC_S     12                  // max accepted centers per round
#define MB_RWORDS  (FPS_NBLK * SPEC_M) // 1024 u64 per round
#define MB_ROUNDS  255                 // hard bound (>=1 accept per round)
#define MB_BYTES   ((size_t)MB_ROUNDS * MB_RWORDS * 8)   // 2,088,960 B

#define NCHUNK     (NPTS / 64)         // 625

// fps key: high 48 bits = f64 dist bits (>=0, monotone as integer),
// low 16 = 0xFFFF - idx (max-dist, tie -> min idx). Nonzero for valid points.
__device__ __forceinline__ unsigned long long fps_mk(double v, unsigned tb) {
    return (((unsigned long long)__double_as_longlong(v)) & 0xFFFFFFFFFFFF0000ull)
         | (unsigned long long)tb;
}
// knn key: min-dist, tie -> min idx.
__device__ __forceinline__ unsigned long long knn_key(double v, int idx) {
    unsigned long long bits = (unsigned long long)__double_as_longlong(v);
    return (bits & 0xFFFFFFFFFFFF0000ull) | (unsigned long long)(unsigned)idx;
}
// distance formula used EVERYWHERE in FPS (f32 inputs, f64 math, fma form)
__device__ __forceinline__ double d3(float px, float py, float pz,
                                     double cx, double cy, double cz) {
    double dx = (double)px - cx, dy = (double)py - cy, dz = (double)pz - cz;
    return fma(dz, dz, fma(dy, dy, dx * dx));
}
__device__ __forceinline__ unsigned long long wave_max_u64(unsigned long long k) {
#pragma unroll
    for (int off = 32; off >= 1; off >>= 1) {
        unsigned long long o = __shfl_xor(k, off, 64);
        k = o > k ? o : k;
    }
    return k;
}

// ---------------- speculative FPS: 64 blocks x 64 threads ----------------
__global__ void __launch_bounds__(FPS_TPB) fps_spec_kernel(
    const float* __restrict__ xyz,            // (2, NPTS, 3)
    float* __restrict__ centers,              // (2, NGRP, 3) in d_out
    unsigned long long* __restrict__ mb)      // [MB_ROUNDS][1024], pre-zeroed
{
    const int bid  = blockIdx.x;
    const int b    = bid >> 5;
    const int lb   = bid & 31;
    const int lane = threadIdx.x;
    const float* __restrict__ X = xyz + (size_t)b * NPTS * 3;
    const int base = lb * FPS_PPB;
    const unsigned tb0 = 0xFFFFu - (unsigned)(base + lane);

    float  px[FPS_PPT], py[FPS_PPT], pz[FPS_PPT];
    double dist[FPS_PPT];
    unsigned vmask = 0;
#pragma unroll
    for (int j = 0; j < FPS_PPT; ++j) {
        int loc = lane + j * FPS_TPB;
        bool ok = loc < FPS_PPB;
        int i   = base + (ok ? loc : 0);
        px[j] = X[i * 3 + 0]; py[j] = X[i * 3 + 1]; pz[j] = X[i * 3 + 2];
        if (ok) vmask |= 1u << j;
    }

    // center 0 = point 0 of the batch
    {
        double cx = (double)X[0], cy = (double)X[1], cz = (double)X[2];
        if (lb == 0 && lane == 0) {
            centers[(size_t)(b * NGRP) * 3 + 0] = X[0];
            centers[(size_t)(b * NGRP) * 3 + 1] = X[1];
            centers[(size_t)(b * NGRP) * 3 + 2] = X[2];
        }
#pragma unroll
        for (int j = 0; j < FPS_PPT; ++j)
            dist[j] = d3(px[j], py[j], pz[j], cx, cy, cz);
    }

#define LANE_RESCAN(OUT)                                                    \
    {                                                                       \
        unsigned long long bb_ = 0ull;                                      \
        _Pragma("unroll")                                                   \
        for (int j_ = 0; j_ < FPS_PPT; ++j_) {                              \
            bool live_ = (((vmask >> j_) & 1u) != 0u) &&                    \
                         (((cons >> j_) & 1u) == 0u);                       \
            unsigned long long kk_ = live_                                  \
                ? fps_mk(dist[j_], tb0 - (unsigned)(j_ << 6)) : 0ull;       \
            bb_ = kk_ > bb_ ? kk_ : bb_;                                    \
        }                                                                   \
        OUT = bb_;                                                          \
    }

    int done = 1;
    int r = 0;

    while (done < NGRP) {
        // ---- per-lane sorted top-4 of current keys ----
        unsigned long long s0 = 0, s1 = 0, s2 = 0, s3 = 0;
#pragma unroll
        for (int j = 0; j < FPS_PPT; ++j) {
            bool live = ((vmask >> j) & 1u) != 0u;
            unsigned long long kk = live ? fps_mk(dist[j], tb0 - (unsigned)(j << 6)) : 0ull;
            unsigned long long t;
            t = kk > s0 ? kk : s0;  kk = kk > s0 ? s0 : kk;  s0 = t;
            t = kk > s1 ? kk : s1;  kk = kk > s1 ? s1 : kk;  s1 = t;
            t = kk > s2 ? kk : s2;  kk = kk > s2 ? s2 : kk;  s2 = t;
            s3 = kk > s3 ? kk : s3;
        }
        unsigned cons = 0;

        // ---- extract block top-16 in order; lane i keeps the i-th max ----
        unsigned long long myMsg = 0;
#pragma unroll
        for (int i = 0; i < SPEC_M; ++i) {
            if (s0 == 0ull) LANE_RESCAN(s0);
            unsigned long long g = wave_max_u64(s0);
            if (s0 == g && g != 0ull) {      // unique keys -> one owner
                unsigned idx = 0xFFFFu - (unsigned)(g & 0xFFFFull);
                unsigned jj  = (idx - (unsigned)(base + lane)) >> 6;
                cons |= 1u << jj;
                s0 = s1; s1 = s2; s2 = s3; s3 = 0ull;
            }
            myMsg = (lane == i) ? g : myMsg;
        }

        // ---- publish: one coalesced 16-lane store ----
        if (lane < SPEC_M)
            __hip_atomic_store(&mb[(size_t)r * MB_RWORDS + bid * SPEC_M + lane], myMsg,
                               __ATOMIC_RELAXED, __HIP_MEMORY_SCOPE_AGENT);

        // ---- poll this batch's 512 fresh words (8 per lane, coalesced) ----
        const unsigned long long* pb = mb + (size_t)r * MB_RWORDS + b * (FPS_BPB * SPEC_M);
        unsigned long long w[8];
#pragma unroll
        for (int q = 0; q < 8; ++q)
            w[q] = __hip_atomic_load(pb + lane + 64 * q,
                                     __ATOMIC_RELAXED, __HIP_MEMORY_SCOPE_AGENT);
        for (;;) {
            bool miss = false;
#pragma unroll
            for (int q = 0; q < 8; ++q) miss |= (w[q] == 0ull);
            if (__ballot(miss) == 0ull) break;
#pragma unroll
            for (int q = 0; q < 8; ++q)
                if (w[q] == 0ull)
                    w[q] = __hip_atomic_load(pb + lane + 64 * q,
                                             __ATOMIC_RELAXED, __HIP_MEMORY_SCOPE_AGENT);
        }

        // ---- guard threshold T = max over blocks of their 16th key ----
        // word index = lane + 64q; within-block pos = (lane+64q)&15 = lane&15.
        unsigned long long tl = 0;
        if ((lane & 15) == 15) {
#pragma unroll
            for (int q = 0; q < 8; ++q) tl = w[q] > tl ? w[q] : tl;
        }
        const unsigned long long T = wave_max_u64(tl);

        // ---- decode candidates: value (trunc48), key, coords ----
        double cv[8]; unsigned long long ck[8];
        float ccx[8], ccy[8], ccz[8];
#pragma unroll
        for (int q = 0; q < 8; ++q) {
            ck[q] = w[q];
            cv[q] = __longlong_as_double((long long)(w[q] & 0xFFFFFFFFFFFF0000ull));
            int ii = 0xFFFF - (int)(w[q] & 0xFFFFull);
            ccx[q] = X[ii * 3 + 0]; ccy[q] = X[ii * 3 + 1]; ccz[q] = X[ii * 3 + 2];
        }
        unsigned cons8 = 0;

        // ---- speculative chain: up to SPEC_S exact winners ----
        for (int s = 0; s < SPEC_S; ++s) {
            unsigned long long lk = 0;
#pragma unroll
            for (int q = 0; q < 8; ++q) {
                unsigned long long kk = ((cons8 >> q) & 1u) ? 0ull : ck[q];
                lk = kk > lk ? kk : lk;
            }
            unsigned long long g = wave_max_u64(lk);
            if (s > 0 && g < T) break;       // s=0 is the true full argmax

            // owner lane/slot: keys unique; select coords + mark consumed
            float sx = ccx[0], sy = ccy[0], sz = ccz[0];
#pragma unroll
            for (int q = 0; q < 8; ++q) {
                bool hit = (ck[q] == g);
                cons8 |= hit ? (1u << q) : 0u;
                sx = hit ? ccx[q] : sx;
                sy = hit ? ccy[q] : sy;
                sz = hit ? ccz[q] : sz;
            }
            unsigned long long om = __ballot(lk == g);
            int owner = __ffsll((long long)om) - 1;
            float wx = __shfl(sx, owner, 64);
            float wy = __shfl(sy, owner, 64);
            float wz = __shfl(sz, owner, 64);
            if (lb == 0 && lane == 0) {
                centers[((size_t)b * NGRP + done) * 3 + 0] = wx;
                centers[((size_t)b * NGRP + done) * 3 + 1] = wy;
                centers[((size_t)b * NGRP + done) * 3 + 2] = wz;
            }
            double Wx = (double)wx, Wy = (double)wy, Wz = (double)wz;
#pragma unroll
            for (int q = 0; q < 8; ++q) {
                double d = d3(ccx[q], ccy[q], ccz[q], Wx, Wy, Wz);
                cv[q] = fmin(cv[q], d);
                ck[q] = (((unsigned long long)__double_as_longlong(cv[q]))
                         & 0xFFFFFFFFFFFF0000ull) | (ck[q] & 0xFFFFull);
            }
#pragma unroll
            for (int j = 0; j < FPS_PPT; ++j)
                dist[j] = fmin(dist[j], d3(px[j], py[j], pz[j], Wx, Wy, Wz));
            ++done;
            if (done == NGRP) break;
        }
        ++r;
    }
#undef LANE_RESCAN
}

// ---------------- R4-proven fallback FPS (1 key/block/iter) ----------------
__global__ void __launch_bounds__(FPS_TPB) fps_kernel(
    const float* __restrict__ xyz,
    float* __restrict__ centers,
    unsigned long long* __restrict__ keys)    // [255][64], pre-zeroed
{
    const int bid  = blockIdx.x;
    const int b    = bid >> 5;
    const int lb   = bid & 31;
    const int lane = threadIdx.x;
    const float* __restrict__ X = xyz + (size_t)b * NPTS * 3;
    const int base  = lb * FPS_PPB;
    const int gbase = base + lane;

    double px[FPS_PPT], py[FPS_PPT], pz[FPS_PPT], dist[FPS_PPT];
#pragma unroll
    for (int j = 0; j < FPS_PPT; ++j) {
        int loc = lane + j * FPS_TPB;
        bool ok = loc < FPS_PPB;
        int i   = base + (ok ? loc : 0);
        px[j] = (double)X[i * 3 + 0];
        py[j] = (double)X[i * 3 + 1];
        pz[j] = (double)X[i * 3 + 2];
        dist[j] = ok ? 1e18 : -1.0;
    }
    double cx = (double)X[0], cy = (double)X[1], cz = (double)X[2];
    if (lb == 0 && lane == 0) {
        centers[(size_t)(b * NGRP) * 3 + 0] = X[0];
        centers[(size_t)(b * NGRP) * 3 + 1] = X[1];
        centers[(size_t)(b * NGRP) * 3 + 2] = X[2];
    }
    for (int it = 0; it < NGRP - 1; ++it) {
        double bd = -2.0; int bj = 0;
#pragma unroll
        for (int j = 0; j < FPS_PPT; ++j) {
            double dx = px[j] - cx, dy = py[j] - cy, dz = pz[j] - cz;
            double d  = fma(dz, dz, fma(dy, dy, dx * dx));
            double nd = dist[j] < d ? dist[j] : d;
            dist[j] = nd;
            bool better = nd > bd;
            bd = better ? nd : bd;
            bj = better ? j  : bj;
        }
        unsigned long long key = fps_mk(bd, 0xFFFFu - (unsigned)(gbase + (bj << 6)));
        key = wave_max_u64(key);
        if (lane == 0)
            __hip_atomic_store(&keys[it * FPS_NBLK + bid], key,
                               __ATOMIC_RELAXED, __HIP_MEMORY_SCOPE_AGENT);
        unsigned long long pk = 0;
        if (lane < FPS_BPB) {
            const unsigned long long* sp = &keys[it * FPS_NBLK + b * FPS_BPB + lane];
            do {
                pk = __hip_atomic_load(sp, __ATOMIC_RELAXED, __HIP_MEMORY_SCOPE_AGENT);
            } while (pk == 0ull);
        }
        unsigned long long g = wave_max_u64(pk);
        int widx = 0xFFFF - (int)(g & 0xFFFFull);
        float wx = X[widx * 3 + 0], wy = X[widx * 3 + 1], wz = X[widx * 3 + 2];
        cx = (double)wx; cy = (double)wy; cz = (double)wz;
        if (lb == 0 && lane == 0) {
            centers[(size_t)(b * NGRP + it + 1) * 3 + 0] = wx;
            centers[(size_t)(b * NGRP + it + 1) * 3 + 1] = wy;
            centers[(size_t)(b * NGRP + it + 1) * 3 + 2] = wz;
        }
    }
}

// ---------------- KNN: 512 blocks x 256 threads (R4-proven) ----------------
__global__ void __launch_bounds__(256) knn_kernel(
    const float* __restrict__ xyz,
    const int*   __restrict__ valid,
    const float* __restrict__ centers,
    int*   __restrict__ knn_idx,
    float* __restrict__ mask)
{
    const int c    = blockIdx.x;
    const int b    = c >> 8;
    const int tid  = threadIdx.x;
    const int wid  = tid >> 6;
    const int lane = tid & 63;
    const float* __restrict__ X = xyz + (size_t)b * NPTS * 3;

    const double cx = (double)centers[(size_t)c * 3 + 0];
    const double cy = (double)centers[(size_t)c * 3 + 1];
    const double cz = (double)centers[(size_t)c * 3 + 2];

    unsigned long long slot;
    {
        int i = wid * 64 + lane;
        float x = X[i * 3 + 0], y = X[i * 3 + 1], z = X[i * 3 + 2];
        double dx = (double)x - cx, dy = (double)y - cy, dz = (double)z - cz;
        slot = knn_key(dx * dx + dy * dy + dz * dz, i);
    }
    unsigned long long tau = wave_max_u64(slot);

    float ax, ay, az, bx, by, bz;
    {
        int ia = (wid + 4) * 64 + lane;
        ax = X[ia * 3 + 0]; ay = X[ia * 3 + 1]; az = X[ia * 3 + 2];
        int sb = wid + 8 < NCHUNK ? wid + 8 : NCHUNK - 1;
        int ib = sb * 64 + lane;
        bx = X[ib * 3 + 0]; by = X[ib * 3 + 1]; bz = X[ib * 3 + 2];
    }
    for (int s = wid + 4; s < NCHUNK; s += 4) {
        float x = ax, y = ay, z = az;
        ax = bx; ay = by; az = bz;
        int sp = s + 8 < NCHUNK ? s + 8 : NCHUNK - 1;
        int ip = sp * 64 + lane;
        bx = X[ip * 3 + 0]; by = X[ip * 3 + 1]; bz = X[ip * 3 + 2];

        int i = s * 64 + lane;
        double dx = (double)x - cx, dy = (double)y - cy, dz = (double)z - cz;
        unsigned long long key = knn_key(dx * dx + dy * dy + dz * dz, i);

        unsigned long long cand = __ballot(key < tau);
        while (cand) {
            int l = __ffsll(cand) - 1;
            cand &= cand - 1;
            unsigned long long kc = __shfl(key, l, 64);
            if (kc < tau) {
                unsigned long long om = __ballot(slot == tau);
                int owner = __ffsll(om) - 1;
                if (lane == owner) slot = kc;
                tau = wave_max_u64(slot);
            }
        }
    }

    __shared__ unsigned long long skey[256];
    skey[tid] = slot;
    __syncthreads();
#pragma unroll
    for (int k = 2; k <= 256; k <<= 1) {
        for (int j = k >> 1; j > 0; j >>= 1) {
            int ixj = tid ^ j;
            if (ixj > tid) {
                unsigned long long a = skey[tid], bb = skey[ixj];
                bool up = ((tid & k) == 0);
                if ((a > bb) == up) { skey[tid] = bb; skey[ixj] = a; }
            }
            __syncthreads();
        }
    }
    if (wid == 0) {
        int idx = (int)(skey[lane] & 0xFFFFull);
        knn_idx[c * GSZ + lane] = idx;
        int v = valid[b * NPTS + idx];
        unsigned long long vb = __ballot(v != 0);
        if (lane == 0) mask[c] = vb ? 1.0f : 0.0f;
    }
}

// ---------------- Aggregation: 512 blocks x 768 threads (R4-proven) ----------------
__global__ void __launch_bounds__(FDIM) agg_kernel(
    const float* __restrict__ fts,
    const int*   __restrict__ knn_idx,
    float* __restrict__ all_fts)
{
    const int c   = blockIdx.x;
    const int b   = c >> 8;
    const int tid = threadIdx.x;
    __shared__ int nbr[GSZ];
    if (tid < GSZ) nbr[tid] = knn_idx[c * GSZ + tid];
    __syncthreads();
    const float* __restrict__ F = fts + (size_t)b * NPTS * FDIM;
    float a0 = 0.f, a1 = 0.f, a2 = 0.f, a3 = 0.f;
    float a4 = 0.f, a5 = 0.f, a6 = 0.f, a7 = 0.f;
#pragma unroll 1
    for (int j = 0; j < GSZ; j += 8) {
        a0 += F[(size_t)nbr[j + 0] * FDIM + tid];
        a1 += F[(size_t)nbr[j + 1] * FDIM + tid];
        a2 += F[(size_t)nbr[j + 2] * FDIM + tid];
        a3 += F[(size_t)nbr[j + 3] * FDIM + tid];
        a4 += F[(size_t)nbr[j + 4] * FDIM + tid];
        a5 += F[(size_t)nbr[j + 5] * FDIM + tid];
        a6 += F[(size_t)nbr[j + 6] * FDIM + tid];
        a7 += F[(size_t)nbr[j + 7] * FDIM + tid];
    }
    all_fts[(size_t)c * FDIM + tid] =
        (((a0 + a1) + (a2 + a3)) + ((a4 + a5) + (a6 + a7))) * 0.015625f;
}

extern "C" void kernel_launch(void* const* d_in, const int* in_sizes, int n_in,
                              void* d_out, int out_size, void* d_ws, size_t ws_size,
                              hipStream_t stream) {
    const float* xyz   = (const float*)d_in[0];
    const float* fts   = (const float*)d_in[1];
    const int*   valid = (const int*)d_in[2];

    float* out     = (float*)d_out;
    float* all_fts = out;                                  // (2,256,768)
    float* mask    = out + (size_t)BATCH * NGRP * FDIM;    // (2,256)
    float* centers = mask + (size_t)BATCH * NGRP;          // (2,256,3)

    const size_t need_spec = MB_BYTES + (size_t)BATCH * NGRP * GSZ * 4;

    if (ws_size >= need_spec) {
        unsigned long long* mb = (unsigned long long*)d_ws;
        int* knn_idx = (int*)((char*)d_ws + MB_BYTES);
        hipMemsetAsync(d_ws, 0, MB_BYTES, stream);   // fresh mailbox every call
        fps_spec_kernel<<<dim3(FPS_NBLK), dim3(FPS_TPB), 0, stream>>>(xyz, centers, mb);
        knn_kernel<<<dim3(BATCH * NGRP), dim3(256), 0, stream>>>(xyz, valid, centers, knn_idx, mask);
        agg_kernel<<<dim3(BATCH * NGRP), dim3(FDIM), 0, stream>>>(fts, knn_idx, all_fts);
    } else {
        // fallback: R4-proven path (small workspace)
        unsigned long long* keys = (unsigned long long*)d_ws;   // 255*64*8 = 130560 B
        int* knn_idx = (int*)((char*)d_ws + 131072);            // 512*64*4
        hipMemsetAsync(d_ws, 0, 131072, stream);
        fps_kernel<<<dim3(FPS_NBLK), dim3(FPS_TPB), 0, stream>>>(xyz, centers, keys);
        knn_kernel<<<dim3(BATCH * NGRP), dim3(256), 0, stream>>>(xyz, valid, centers, knn_idx, mask);
        agg_kernel<<<dim3(BATCH * NGRP), dim3(FDIM), 0, stream>>>(fts, knn_idx, all_fts);
    }
}